// Round 2
// baseline (4988.046 us; speedup 1.0000x reference)
//
#include <hip/hip_runtime.h>
#include <hip/hip_bf16.h>

#define VN    64
#define HSTR  260   // fp32 row stride: 260%32=4 -> adjacent rows offset 4 banks
#define KC    16    // K-chunk staged per matmul step

// acc[4][16] += sh_h(64 x Kpad) @ Wg(FIN x 256), rows k>=FIN treated as zero.
// thread (tm,tn): nodes tm*4+mm, features tn*16+j
__device__ __forceinline__ void mm_acc(const float* __restrict__ Wg,
                                       int FIN, int Kpad,
                                       float acc[4][16],
                                       const float (*shh)[HSTR],
                                       float (*shw)[HSTR],
                                       int tm, int tn, int tid)
{
  for (int kc = 0; kc < Kpad; kc += KC) {
    // stage KC x 256 weight rows, coalesced over f
    for (int i = tid; i < KC * 256; i += 256) {
      int kl = i >> 8, f = i & 255;
      int k = kc + kl;
      shw[kl][f] = (k < FIN) ? Wg[k * 256 + f] : 0.0f;
    }
    __syncthreads();
#pragma unroll
    for (int kl = 0; kl < KC; kl++) {
      float a0 = shh[tm * 4 + 0][kc + kl];
      float a1 = shh[tm * 4 + 1][kc + kl];
      float a2 = shh[tm * 4 + 2][kc + kl];
      float a3 = shh[tm * 4 + 3][kc + kl];
      float bv[16];
#pragma unroll
      for (int j = 0; j < 16; j++) bv[j] = shw[kl][tn * 16 + j];
#pragma unroll
      for (int j = 0; j < 16; j++) {
        acc[0][j] = fmaf(a0, bv[j], acc[0][j]);
        acc[1][j] = fmaf(a1, bv[j], acc[1][j]);
        acc[2][j] = fmaf(a2, bv[j], acc[2][j]);
        acc[3][j] = fmaf(a3, bv[j], acc[3][j]);
      }
    }
    __syncthreads();
  }
}

__global__ __launch_bounds__(256)
void gat_poly_kernel(const float* __restrict__ x,
                     const int* __restrict__ t,
                     const float* __restrict__ tW,
                     const float* __restrict__ tb,
                     const float* __restrict__ W0, const float* __restrict__ as0,
                     const float* __restrict__ at0, const float* __restrict__ b0,
                     const float* __restrict__ W1, const float* __restrict__ as1,
                     const float* __restrict__ at1, const float* __restrict__ b1,
                     const float* __restrict__ W2, const float* __restrict__ as2,
                     const float* __restrict__ at2, const float* __restrict__ b2,
                     const float* __restrict__ W3, const float* __restrict__ as3,
                     const float* __restrict__ at3, const float* __restrict__ b3,
                     const float* __restrict__ sk0, const float* __restrict__ sk1,
                     const float* __restrict__ sk2,
                     const float* __restrict__ h1W, const float* __restrict__ h1b,
                     const float* __restrict__ h2W, const float* __restrict__ h2b,
                     float* __restrict__ out)
{
  __shared__ float sh_h[VN][HSTR];     // activations (fp32 across layers)
  __shared__ float sh_proj[VN][HSTR];  // h @ W
  __shared__ float sh_wt[KC][HSTR];    // staged weight chunk
  __shared__ float sh_emb[128];
  __shared__ float sh_temb[128];
  __shared__ float sh_ss[VN][4];
  __shared__ float sh_st[VN][4];
  __shared__ float sh_al[VN][4][3];

  const int b   = blockIdx.x;
  const int tid = threadIdx.x;
  const int tm  = tid >> 4;   // node group (4 nodes)
  const int tn  = tid & 15;   // feature group (16 feats)

  // ---------------- time embedding: silu(sinemb(t) @ tW + tb) ----------------
  if (tid < 64) {
    float fr = expf(-logf(10000.0f) * (float)tid / 63.0f);
    float te = (float)t[b] * fr;
    sh_emb[tid]      = sinf(te);
    sh_emb[tid + 64] = cosf(te);
  }
  __syncthreads();
  if (tid < 128) {
    float a = tb[tid];
    for (int k = 0; k < 128; k++)
      a = fmaf(sh_emb[k], tW[k * 128 + tid], a);
    sh_temb[tid] = a / (1.0f + expf(-a));   // silu
  }
  __syncthreads();

  // ---------------- h0 = [coords(2), pos(4), temb(128)], zero-pad to 160 -----
  for (int idx = tid; idx < VN * 160; idx += 256) {
    int n = idx / 160, k = idx - n * 160;
    float v = 0.0f;
    if (k < 2) {
      v = x[b * 128 + 2 * n + k];
    } else if (k < 6) {
      float ph  = (float)n * 0.09817477042468103f;  // 2*pi/64
      float arg = (k < 4) ? ph : 2.0f * ph;
      v = ((k & 1) == 0) ? sinf(arg) : cosf(arg);   // k=2 sin, 3 cos, 4 sin2, 5 cos2
    } else if (k < 134) {
      v = sh_temb[k - 6];
    }
    sh_h[n][k] = v;
  }
  __syncthreads();

  const float* Ws[3]  = {W0, W1, W2};
  const float* Sks[3] = {sk0, sk1, sk2};
  const float* Asr[3] = {as0, as1, as2};
  const float* Atg[3] = {at0, at1, at2};
  const float* Bs[3]  = {b0, b1, b2};
  const int FINs[3]  = {134, 256, 256};
  const int Kpads[3] = {160, 256, 256};

  // ---------------- GAT layers 0..2 (NH=4, FOUT=64, concat + elu) ------------
  for (int li = 0; li < 3; li++) {
    float acc[4][16];
#pragma unroll
    for (int mm = 0; mm < 4; mm++)
#pragma unroll
      for (int j = 0; j < 16; j++) acc[mm][j] = 0.0f;

    mm_acc(Ws[li], FINs[li], Kpads[li], acc, sh_h, sh_wt, tm, tn, tid);

#pragma unroll
    for (int mm = 0; mm < 4; mm++)
#pragma unroll
      for (int j = 0; j < 16; j++) sh_proj[tm * 4 + mm][tn * 16 + j] = acc[mm][j];
    __syncthreads();

    { // attention scores s_src/s_tgt: thread = (node, head)
      int n = tid >> 2, hd = tid & 3;
      const float* av = Asr[li];
      const float* tv = Atg[li];
      float ss = 0.0f, st = 0.0f;
      for (int f = 0; f < 64; f++) {
        float p = sh_proj[n][hd * 64 + f];
        ss = fmaf(p, av[hd * 64 + f], ss);
        st = fmaf(p, tv[hd * 64 + f], st);
      }
      sh_ss[n][hd] = ss;
      sh_st[n][hd] = st;
    }
    __syncthreads();
    { // softmax over the 3 incoming edges {prev, next, self}
      int n = tid >> 2, hd = tid & 3;
      int prv = (n + 63) & 63, nxt = (n + 1) & 63;
      float stg = sh_st[n][hd];
      float e0 = sh_ss[prv][hd] + stg; e0 = (e0 < 0.0f) ? 0.2f * e0 : e0;
      float e1 = sh_ss[nxt][hd] + stg; e1 = (e1 < 0.0f) ? 0.2f * e1 : e1;
      float e2 = sh_ss[n][hd]   + stg; e2 = (e2 < 0.0f) ? 0.2f * e2 : e2;
      float m  = fmaxf(e0, fmaxf(e1, e2));
      float x0 = expf(e0 - m), x1 = expf(e1 - m), x2 = expf(e2 - m);
      float dn = x0 + x1 + x2 + 1e-16f;
      sh_al[n][hd][0] = x0 / dn;
      sh_al[n][hd][1] = x1 / dn;
      sh_al[n][hd][2] = x2 / dn;
    }
    __syncthreads();

    // skip projection into acc
#pragma unroll
    for (int mm = 0; mm < 4; mm++)
#pragma unroll
      for (int j = 0; j < 16; j++) acc[mm][j] = 0.0f;
    mm_acc(Sks[li], FINs[li], Kpads[li], acc, sh_h, sh_wt, tm, tn, tid);

    // out = skip + sum_k alpha_k * proj[src_k] + bias; elu; -> sh_h
    const float* bb = Bs[li];
    const int hd = tn >> 2;   // head = f/64, constant per thread
#pragma unroll
    for (int mm = 0; mm < 4; mm++) {
      int n = tm * 4 + mm;
      int prv = (n + 63) & 63, nxt = (n + 1) & 63;
      float a0 = sh_al[n][hd][0], a1 = sh_al[n][hd][1], a2 = sh_al[n][hd][2];
#pragma unroll
      for (int j = 0; j < 16; j++) {
        int f = tn * 16 + j;
        float o = acc[mm][j]
                + a0 * sh_proj[prv][f] + a1 * sh_proj[nxt][f] + a2 * sh_proj[n][f]
                + bb[f];
        o = (o > 0.0f) ? o : (expf(o) - 1.0f);   // elu
        sh_h[n][f] = o;
      }
    }
    __syncthreads();
  }

  // ---------------- GAT layer 3 (NH=1, FOUT=256, identity skip, no act) ------
  {
    float acc[4][16];
#pragma unroll
    for (int mm = 0; mm < 4; mm++)
#pragma unroll
      for (int j = 0; j < 16; j++) acc[mm][j] = 0.0f;
    mm_acc(W3, 256, 256, acc, sh_h, sh_wt, tm, tn, tid);
#pragma unroll
    for (int mm = 0; mm < 4; mm++)
#pragma unroll
      for (int j = 0; j < 16; j++) sh_proj[tm * 4 + mm][tn * 16 + j] = acc[mm][j];
    __syncthreads();

    if (tid < 128) {  // full-width scores (FOUT=256, single head)
      int n = tid & 63;
      const float* av = (tid < 64) ? as3 : at3;
      float s = 0.0f;
      for (int f = 0; f < 256; f++) s = fmaf(sh_proj[n][f], av[f], s);
      if (tid < 64) sh_ss[n][0] = s; else sh_st[n][0] = s;
    }
    __syncthreads();
    if (tid < 64) {
      int n = tid;
      int prv = (n + 63) & 63, nxt = (n + 1) & 63;
      float stg = sh_st[n][0];
      float e0 = sh_ss[prv][0] + stg; e0 = (e0 < 0.0f) ? 0.2f * e0 : e0;
      float e1 = sh_ss[nxt][0] + stg; e1 = (e1 < 0.0f) ? 0.2f * e1 : e1;
      float e2 = sh_ss[n][0]   + stg; e2 = (e2 < 0.0f) ? 0.2f * e2 : e2;
      float m  = fmaxf(e0, fmaxf(e1, e2));
      float x0 = expf(e0 - m), x1 = expf(e1 - m), x2 = expf(e2 - m);
      float dn = x0 + x1 + x2 + 1e-16f;
      sh_al[n][0][0] = x0 / dn;
      sh_al[n][0][1] = x1 / dn;
      sh_al[n][0][2] = x2 / dn;
    }
    __syncthreads();

#pragma unroll
    for (int mm = 0; mm < 4; mm++) {
      int n = tm * 4 + mm;
      int prv = (n + 63) & 63, nxt = (n + 1) & 63;
      float a0 = sh_al[n][0][0], a1 = sh_al[n][0][1], a2 = sh_al[n][0][2];
#pragma unroll
      for (int j = 0; j < 16; j++) {
        int f = tn * 16 + j;
        float o = a0 * sh_proj[prv][f] + a1 * sh_proj[nxt][f] + a2 * sh_proj[n][f]
                + sh_h[n][f] + b3[f];   // identity residual, no activation
        sh_h[n][f] = o;   // each (n,f) owned by exactly one thread
      }
    }
    __syncthreads();
  }

  // ---------------- head MLP: silu(h@h1W+h1b) then h@h2W+h2b -----------------
  {
    float acc[4][16];
#pragma unroll
    for (int mm = 0; mm < 4; mm++)
#pragma unroll
      for (int j = 0; j < 16; j++) acc[mm][j] = 0.0f;
    mm_acc(h1W, 256, 256, acc, sh_h, sh_wt, tm, tn, tid);
#pragma unroll
    for (int mm = 0; mm < 4; mm++) {
      int n = tm * 4 + mm;
#pragma unroll
      for (int j = 0; j < 16; j++) {
        int f = tn * 16 + j;
        float o = acc[mm][j] + h1b[f];
        sh_h[n][f] = o / (1.0f + expf(-o));   // silu
      }
    }
    __syncthreads();

    if (tid < 128) {  // final 256 -> 2 projection, one thread per (node, coord)
      int n = tid >> 1, c = tid & 1;
      float o = h2b[c];
      for (int k = 0; k < 256; k++)
        o = fmaf(sh_h[n][k], h2W[k * 2 + c], o);
      out[b * 128 + 2 * n + c] = o;
    }
  }
}

extern "C" void kernel_launch(void* const* d_in, const int* in_sizes, int n_in,
                              void* d_out, int out_size, void* d_ws, size_t ws_size,
                              hipStream_t stream)
{
  auto fp = [&](int i) { return (const float*)d_in[i]; };
  gat_poly_kernel<<<2048, 256, 0, stream>>>(
      fp(0), (const int*)d_in[1], fp(2), fp(3),
      fp(4),  fp(5),  fp(6),  fp(7),    // W0 asrc0 atgt0 b0
      fp(8),  fp(9),  fp(10), fp(11),   // W1 ...
      fp(12), fp(13), fp(14), fp(15),   // W2 ...
      fp(16), fp(17), fp(18), fp(19),   // W3 ...
      fp(20), fp(21), fp(22),           // skip0..2
      fp(23), fp(24), fp(25), fp(26),   // h1W h1b h2W h2b
      (float*)d_out);
}

// Round 3
// 682.929 us; speedup vs baseline: 7.3039x; 7.3039x over previous
//
#include <hip/hip_runtime.h>
#include <hip/hip_bf16.h>

#define VN    64
#define KPAD  264   // bf16 elements per sh_hb row (row stride 528B: %32dw=4 -> 2-way max, free)
#define PSTR  260   // fp32 elements per sh_proj row

typedef __bf16 bf16x8 __attribute__((ext_vector_type(8)));
typedef float  f32x4  __attribute__((ext_vector_type(4)));

// packed-weight element offsets in d_ws (bf16 elements)
// order: W0(160x256) sk0(160x256) W1 sk1 W2 sk2 W3 h1W (256x256 each)
#define OFF_W0   0
#define OFF_SK0  40960
#define OFF_W1   81920
#define OFF_SK1  147456
#define OFF_W2   212992
#define OFF_SK2  278528
#define OFF_W3   344064
#define OFF_H1W  409600

// fp32 (fin x 256) -> bf16 packed fragment layout:
// dst[((k>>3)*256 + n)*8 + (k&7)] ; rows k>=fin zeroed. dst idx == linear idx.
__global__ void conv_pack(const float* __restrict__ src, __bf16* __restrict__ dst,
                          int fin, int kp)
{
  int idx = blockIdx.x * 256 + threadIdx.x;
  if (idx >= kp * 256) return;
  int r = idx & 7, n = (idx >> 3) & 255, c = idx >> 11;
  int k = c * 8 + r;
  float v = (k < fin) ? src[k * 256 + n] : 0.0f;
  dst[idx] = (__bf16)v;
}

// acc[4x4 tiles] += A(64 x 32*KS from LDS) @ B(packed global). Wave owns 64 cols.
template<int KS>
__device__ __forceinline__ void mfma_mm(const __bf16* __restrict__ Bp,
                                        f32x4 acc[4][4],
                                        const __bf16* __restrict__ shA,
                                        int l, int q, int colbase8)
{
#pragma unroll
  for (int s = 0; s < KS; s++) {
    bf16x8 af[4], bfr[4];
#pragma unroll
    for (int rt = 0; rt < 4; rt++)
      af[rt] = *(const bf16x8*)(shA + (rt * 16 + l) * KPAD + s * 32 + q * 8);
#pragma unroll
    for (int ct = 0; ct < 4; ct++)
      bfr[ct] = *(const bf16x8*)(Bp + (s * 4 + q) * 2048 + colbase8 + ct * 128);
#pragma unroll
    for (int rt = 0; rt < 4; rt++)
#pragma unroll
      for (int ct = 0; ct < 4; ct++)
        acc[rt][ct] = __builtin_amdgcn_mfma_f32_16x16x32_bf16(af[rt], bfr[ct], acc[rt][ct], 0, 0, 0);
  }
}

__global__ __launch_bounds__(256, 1)
void gat_poly_kernel(const float* __restrict__ x,
                     const int* __restrict__ t,
                     const float* __restrict__ tW,
                     const float* __restrict__ tb,
                     const float* __restrict__ as0, const float* __restrict__ at0, const float* __restrict__ b0,
                     const float* __restrict__ as1, const float* __restrict__ at1, const float* __restrict__ b1,
                     const float* __restrict__ as2, const float* __restrict__ at2, const float* __restrict__ b2,
                     const float* __restrict__ as3, const float* __restrict__ at3, const float* __restrict__ b3,
                     const float* __restrict__ h1b,
                     const float* __restrict__ h2W, const float* __restrict__ h2b,
                     const __bf16* __restrict__ WP,   // packed weights in d_ws
                     float* __restrict__ out)
{
  __shared__ __bf16 sh_hb[VN * KPAD];   // activations, bf16 (MFMA A source)
  __shared__ float  sh_proj[VN * PSTR]; // proj, fp32
  __shared__ float  sh_emb[128];
  __shared__ float  sh_temb[128];
  __shared__ float  sh_ssp[VN * 4];     // per-wave score partials (src)
  __shared__ float  sh_stp[VN * 4];     // per-wave score partials (tgt)
  __shared__ float  sh_al[VN][4][3];    // softmax alphas [node][head][edge]

  const int b    = blockIdx.x;
  const int tid  = threadIdx.x;
  const int w    = tid >> 6;          // wave id = col group = head (layers 0-2)
  const int lane = tid & 63;
  const int l    = lane & 15;
  const int q    = lane >> 4;
  const int cb   = w * 64;            // col base
  const int colbase8 = (cb + l) * 8;

  float h_reg[4][4][4];               // lane's fp32 copy of h[n][f] (C-layout ownership)

  // ---------------- time embedding: silu(sinemb(t) @ tW + tb) ----------------
  if (tid < 64) {
    float fr = expf(-logf(10000.0f) * (float)tid / 63.0f);
    float te = (float)t[b] * fr;
    sh_emb[tid]      = sinf(te);
    sh_emb[tid + 64] = cosf(te);
  }
  __syncthreads();
  if (tid < 128) {
    float a = tb[tid];
    for (int k = 0; k < 128; k++)
      a = fmaf(sh_emb[k], tW[k * 128 + tid], a);
    sh_temb[tid] = a / (1.0f + expf(-a));
  }
  __syncthreads();

  // ------------- h0 = [coords(2), pos(4), temb(128)], zero pad to 160 --------
  for (int idx = tid; idx < VN * 160; idx += 256) {
    int n = idx / 160, k = idx - n * 160;
    float v = 0.0f;
    if (k < 2) {
      v = x[b * 128 + 2 * n + k];
    } else if (k < 6) {
      float ph  = (float)n * 0.09817477042468103f;  // 2*pi/64
      float arg = (k < 4) ? ph : 2.0f * ph;
      v = ((k & 1) == 0) ? sinf(arg) : cosf(arg);
    } else if (k < 134) {
      v = sh_temb[k - 6];
    }
    sh_hb[n * KPAD + k] = (__bf16)v;
  }
  __syncthreads();

  const int WOFFS[3]  = {OFF_W0, OFF_W1, OFF_W2};
  const int SOFFS[3]  = {OFF_SK0, OFF_SK1, OFF_SK2};
  const float* Asr[3] = {as0, as1, as2};
  const float* Atg[3] = {at0, at1, at2};
  const float* Bs[3]  = {b0, b1, b2};

  // ---------------- GAT layers 0..2 (NH=4, FOUT=64, concat + elu) ------------
  for (int li = 0; li < 3; li++) {
    f32x4 acc[4][4];
#pragma unroll
    for (int rt = 0; rt < 4; rt++)
#pragma unroll
      for (int ct = 0; ct < 4; ct++) acc[rt][ct] = (f32x4)0.0f;

    if (li == 0) mfma_mm<5>(WP + WOFFS[0], acc, sh_hb, l, q, colbase8);
    else         mfma_mm<8>(WP + WOFFS[li], acc, sh_hb, l, q, colbase8);

    { // scores from registers: wave w == head w (cols 64w..64w+63)
      const float* av = Asr[li];
      const float* tv = Atg[li];
      float a0 = av[cb + l], a1 = av[cb + 16 + l], a2 = av[cb + 32 + l], a3 = av[cb + 48 + l];
      float t0 = tv[cb + l], t1 = tv[cb + 16 + l], t2 = tv[cb + 32 + l], t3 = tv[cb + 48 + l];
#pragma unroll
      for (int rt = 0; rt < 4; rt++)
#pragma unroll
        for (int reg = 0; reg < 4; reg++) {
          float ss = acc[rt][0][reg] * a0 + acc[rt][1][reg] * a1
                   + acc[rt][2][reg] * a2 + acc[rt][3][reg] * a3;
          float st = acc[rt][0][reg] * t0 + acc[rt][1][reg] * t1
                   + acc[rt][2][reg] * t2 + acc[rt][3][reg] * t3;
#pragma unroll
          for (int m = 8; m >= 1; m >>= 1) {
            ss += __shfl_xor(ss, m, 64);
            st += __shfl_xor(st, m, 64);
          }
          if (l == 0) {
            int n = rt * 16 + q * 4 + reg;
            sh_ssp[n * 4 + w] = ss;
            sh_stp[n * 4 + w] = st;
          }
        }
    }
    // spill proj to LDS (fp32) for neighbor gathers
#pragma unroll
    for (int rt = 0; rt < 4; rt++)
#pragma unroll
      for (int ct = 0; ct < 4; ct++)
#pragma unroll
        for (int reg = 0; reg < 4; reg++)
          sh_proj[(rt * 16 + q * 4 + reg) * PSTR + cb + ct * 16 + l] = acc[rt][ct][reg];
    __syncthreads();

    { // softmax over 3 incoming edges, thread per (node, head)
      int n = tid >> 2, hd = tid & 3;
      int prv = (n + 63) & 63, nxt = (n + 1) & 63;
      float stg = sh_stp[n * 4 + hd];
      float e0 = sh_ssp[prv * 4 + hd] + stg; e0 = (e0 < 0.0f) ? 0.2f * e0 : e0;
      float e1 = sh_ssp[nxt * 4 + hd] + stg; e1 = (e1 < 0.0f) ? 0.2f * e1 : e1;
      float e2 = sh_ssp[n * 4 + hd]   + stg; e2 = (e2 < 0.0f) ? 0.2f * e2 : e2;
      float m  = fmaxf(e0, fmaxf(e1, e2));
      float x0 = expf(e0 - m), x1 = expf(e1 - m), x2 = expf(e2 - m);
      float dn = x0 + x1 + x2 + 1e-16f;
      sh_al[n][hd][0] = x0 / dn;
      sh_al[n][hd][1] = x1 / dn;
      sh_al[n][hd][2] = x2 / dn;
    }

    // skip projection
#pragma unroll
    for (int rt = 0; rt < 4; rt++)
#pragma unroll
      for (int ct = 0; ct < 4; ct++) acc[rt][ct] = (f32x4)0.0f;
    if (li == 0) mfma_mm<5>(WP + SOFFS[0], acc, sh_hb, l, q, colbase8);
    else         mfma_mm<8>(WP + SOFFS[li], acc, sh_hb, l, q, colbase8);
    __syncthreads();   // sh_al ready; all waves done reading sh_hb

    { // epilogue: out = skip + sum alpha*proj[src] + b; elu -> h_reg, sh_hb
      const float* bb = Bs[li];
      float b4[4];
#pragma unroll
      for (int ct = 0; ct < 4; ct++) b4[ct] = bb[cb + ct * 16 + l];
#pragma unroll
      for (int rt = 0; rt < 4; rt++)
#pragma unroll
        for (int reg = 0; reg < 4; reg++) {
          int n = rt * 16 + q * 4 + reg;
          int prv = (n + 63) & 63, nxt = (n + 1) & 63;
          float a0 = sh_al[n][w][0], a1 = sh_al[n][w][1], a2 = sh_al[n][w][2];
#pragma unroll
          for (int ct = 0; ct < 4; ct++) {
            int f = cb + ct * 16 + l;
            float o = acc[rt][ct][reg]
                    + a0 * sh_proj[prv * PSTR + f]
                    + a1 * sh_proj[nxt * PSTR + f]
                    + a2 * sh_proj[n * PSTR + f] + b4[ct];
            o = (o > 0.0f) ? o : (expf(o) - 1.0f);
            h_reg[rt][ct][reg] = o;
            sh_hb[n * KPAD + f] = (__bf16)o;
          }
        }
    }
    __syncthreads();
  }

  // ---------------- GAT layer 3 (NH=1, FOUT=256, identity skip, no act) ------
  {
    f32x4 acc[4][4];
#pragma unroll
    for (int rt = 0; rt < 4; rt++)
#pragma unroll
      for (int ct = 0; ct < 4; ct++) acc[rt][ct] = (f32x4)0.0f;
    mfma_mm<8>(WP + OFF_W3, acc, sh_hb, l, q, colbase8);

    { // per-wave partial scores over this wave's 64 cols
      float a0 = as3[cb + l], a1 = as3[cb + 16 + l], a2 = as3[cb + 32 + l], a3 = as3[cb + 48 + l];
      float t0 = at3[cb + l], t1 = at3[cb + 16 + l], t2 = at3[cb + 32 + l], t3 = at3[cb + 48 + l];
#pragma unroll
      for (int rt = 0; rt < 4; rt++)
#pragma unroll
        for (int reg = 0; reg < 4; reg++) {
          float ss = acc[rt][0][reg] * a0 + acc[rt][1][reg] * a1
                   + acc[rt][2][reg] * a2 + acc[rt][3][reg] * a3;
          float st = acc[rt][0][reg] * t0 + acc[rt][1][reg] * t1
                   + acc[rt][2][reg] * t2 + acc[rt][3][reg] * t3;
#pragma unroll
          for (int m = 8; m >= 1; m >>= 1) {
            ss += __shfl_xor(ss, m, 64);
            st += __shfl_xor(st, m, 64);
          }
          if (l == 0) {
            int n = rt * 16 + q * 4 + reg;
            sh_ssp[n * 4 + w] = ss;
            sh_stp[n * 4 + w] = st;
          }
        }
    }
#pragma unroll
    for (int rt = 0; rt < 4; rt++)
#pragma unroll
      for (int ct = 0; ct < 4; ct++)
#pragma unroll
        for (int reg = 0; reg < 4; reg++)
          sh_proj[(rt * 16 + q * 4 + reg) * PSTR + cb + ct * 16 + l] = acc[rt][ct][reg];
    __syncthreads();

    if (tid < 64) {  // single head: sum the 4 wave partials
      int n = tid;
      float ssn = sh_ssp[n * 4] + sh_ssp[n * 4 + 1] + sh_ssp[n * 4 + 2] + sh_ssp[n * 4 + 3];
      // tgt partial for node n
      float stn = sh_stp[n * 4] + sh_stp[n * 4 + 1] + sh_stp[n * 4 + 2] + sh_stp[n * 4 + 3];
      sh_ssp[n * 4] = ssn;
      sh_stp[n * 4] = stn;
    }
    __syncthreads();
    if (tid < 64) {
      int n = tid;
      int prv = (n + 63) & 63, nxt = (n + 1) & 63;
      float stg = sh_stp[n * 4];
      float e0 = sh_ssp[prv * 4] + stg; e0 = (e0 < 0.0f) ? 0.2f * e0 : e0;
      float e1 = sh_ssp[nxt * 4] + stg; e1 = (e1 < 0.0f) ? 0.2f * e1 : e1;
      float e2 = sh_ssp[n * 4]   + stg; e2 = (e2 < 0.0f) ? 0.2f * e2 : e2;
      float m  = fmaxf(e0, fmaxf(e1, e2));
      float x0 = expf(e0 - m), x1 = expf(e1 - m), x2 = expf(e2 - m);
      float dn = x0 + x1 + x2 + 1e-16f;
      sh_al[n][0][0] = x0 / dn;
      sh_al[n][0][1] = x1 / dn;
      sh_al[n][0][2] = x2 / dn;
    }
    __syncthreads();

    { // epilogue: out = agg + h (identity residual) + b3, no activation
      float b4[4];
#pragma unroll
      for (int ct = 0; ct < 4; ct++) b4[ct] = b3[cb + ct * 16 + l];
#pragma unroll
      for (int rt = 0; rt < 4; rt++)
#pragma unroll
        for (int reg = 0; reg < 4; reg++) {
          int n = rt * 16 + q * 4 + reg;
          int prv = (n + 63) & 63, nxt = (n + 1) & 63;
          float a0 = sh_al[n][0][0], a1 = sh_al[n][0][1], a2 = sh_al[n][0][2];
#pragma unroll
          for (int ct = 0; ct < 4; ct++) {
            int f = cb + ct * 16 + l;
            float o = a0 * sh_proj[prv * PSTR + f]
                    + a1 * sh_proj[nxt * PSTR + f]
                    + a2 * sh_proj[n * PSTR + f]
                    + h_reg[rt][ct][reg] + b4[ct];
            h_reg[rt][ct][reg] = o;
            sh_hb[n * KPAD + f] = (__bf16)o;
          }
        }
    }
    __syncthreads();
  }

  // ---------------- head MLP: silu(h@h1W+h1b), then h@h2W+h2b ----------------
  {
    f32x4 acc[4][4];
#pragma unroll
    for (int rt = 0; rt < 4; rt++)
#pragma unroll
      for (int ct = 0; ct < 4; ct++) acc[rt][ct] = (f32x4)0.0f;
    mfma_mm<8>(WP + OFF_H1W, acc, sh_hb, l, q, colbase8);
    __syncthreads();   // all waves done reading sh_hb before overwrite

    float b4[4];
#pragma unroll
    for (int ct = 0; ct < 4; ct++) b4[ct] = h1b[cb + ct * 16 + l];
#pragma unroll
    for (int rt = 0; rt < 4; rt++)
#pragma unroll
      for (int reg = 0; reg < 4; reg++) {
        int n = rt * 16 + q * 4 + reg;
#pragma unroll
        for (int ct = 0; ct < 4; ct++) {
          int f = cb + ct * 16 + l;
          float o = acc[rt][ct][reg] + b4[ct];
          o = o / (1.0f + expf(-o));
          sh_hb[n * KPAD + f] = (__bf16)o;
        }
      }
    __syncthreads();

    if (tid < 128) {  // final 256 -> 2 projection
      int n = tid >> 1, c = tid & 1;
      float o = h2b[c];
      for (int k = 0; k < 256; k++)
        o = fmaf((float)sh_hb[n * KPAD + k], h2W[k * 2 + c], o);
      out[b * 128 + 2 * n + c] = o;
    }
  }
}

extern "C" void kernel_launch(void* const* d_in, const int* in_sizes, int n_in,
                              void* d_out, int out_size, void* d_ws, size_t ws_size,
                              hipStream_t stream)
{
  auto fp = [&](int i) { return (const float*)d_in[i]; };
  __bf16* wp = (__bf16*)d_ws;

  // pack weights (fp32 -> bf16, fragment-friendly layout) into d_ws
  conv_pack<<<160, 256, 0, stream>>>(fp(4),  wp + OFF_W0,  134, 160);  // W0
  conv_pack<<<160, 256, 0, stream>>>(fp(20), wp + OFF_SK0, 134, 160);  // skip0
  conv_pack<<<256, 256, 0, stream>>>(fp(8),  wp + OFF_W1,  256, 256);  // W1
  conv_pack<<<256, 256, 0, stream>>>(fp(21), wp + OFF_SK1, 256, 256);  // skip1
  conv_pack<<<256, 256, 0, stream>>>(fp(12), wp + OFF_W2,  256, 256);  // W2
  conv_pack<<<256, 256, 0, stream>>>(fp(22), wp + OFF_SK2, 256, 256);  // skip2
  conv_pack<<<256, 256, 0, stream>>>(fp(16), wp + OFF_W3,  256, 256);  // W3
  conv_pack<<<256, 256, 0, stream>>>(fp(23), wp + OFF_H1W, 256, 256);  // h1W

  gat_poly_kernel<<<2048, 256, 0, stream>>>(
      fp(0), (const int*)d_in[1], fp(2), fp(3),
      fp(5),  fp(6),  fp(7),     // as0 at0 b0
      fp(9),  fp(10), fp(11),    // as1 at1 b1
      fp(13), fp(14), fp(15),    // as2 at2 b2
      fp(17), fp(18), fp(19),    // as3 at3 b3
      fp(24),                    // h1b
      fp(25), fp(26),            // h2W h2b
      wp,
      (float*)d_out);
}

// Round 4
// 519.052 us; speedup vs baseline: 9.6099x; 1.3157x over previous
//
#include <hip/hip_runtime.h>
#include <hip/hip_bf16.h>

#define VN    64
#define KPAD  264   // sh_hb bf16 stride: rows 16B-aligned (528B), %8dw=4 -> ds_read_b128 ok
#define PPAD  268   // sh_pb bf16 stride: scalar access, quad rows hit distinct bank groups

typedef __bf16 bf16x8 __attribute__((ext_vector_type(8)));
typedef float  f32x4  __attribute__((ext_vector_type(4)));

// packed-weight bf16 element offsets in d_ws
#define OFF_W0   0
#define OFF_SK0  40960
#define OFF_W1   81920
#define OFF_SK1  147456
#define OFF_W2   212992
#define OFF_SK2  278528
#define OFF_W3   344064
#define OFF_H1W  409600
#define OFF_END  475136            // end of packed weights (bf16 elems)
// fp32 regions after packed weights (byte 950272, 16B aligned)
// h2wt: 512 fp32 ; temb: 2048*128 fp32

__global__ void conv_pack(const float* __restrict__ src, __bf16* __restrict__ dst,
                          int fin, int kp)
{
  int idx = blockIdx.x * 256 + threadIdx.x;
  if (idx >= kp * 256) return;
  int r = idx & 7, n = (idx >> 3) & 255, c = idx >> 11;
  int k = c * 8 + r;
  float v = (k < fin) ? src[k * 256 + n] : 0.0f;
  dst[idx] = (__bf16)v;
}

__global__ void transpose_h2w(const float* __restrict__ h2W, float* __restrict__ h2wt)
{
  int idx = threadIdx.x;          // 512 threads
  int c = idx >> 8, k = idx & 255;
  h2wt[idx] = h2W[k * 2 + c];
}

// per-polygon time embedding: silu(sinemb(t) @ tW + tb), 2048 blocks x 128 thr
__global__ void temb_kernel(const int* __restrict__ t, const float* __restrict__ tW,
                            const float* __restrict__ tb, float* __restrict__ d_temb)
{
  __shared__ float se[128];
  int b = blockIdx.x, tid = threadIdx.x;
  int fi = tid & 63;
  float fr = expf(-logf(10000.0f) * (float)fi / 63.0f);
  float te = (float)t[b] * fr;
  se[tid] = (tid < 64) ? sinf(te) : cosf(te);
  __syncthreads();
  float a = tb[tid];
  for (int k = 0; k < 128; k++)
    a = fmaf(se[k], tW[k * 128 + tid], a);
  d_temb[b * 128 + tid] = a / (1.0f + expf(-a));
}

// acc[4x4] += A(64 x 32*KS from LDS) @ B(packed global). Wave owns 64 cols.
template<int KS>
__device__ __forceinline__ void mfma_mm(const __bf16* __restrict__ Bp,
                                        f32x4 acc[4][4],
                                        const __bf16* __restrict__ shA,
                                        int l, int q, int colbase8)
{
#pragma unroll
  for (int s = 0; s < KS; s++) {
    bf16x8 af[4], bfr[4];
#pragma unroll
    for (int rt = 0; rt < 4; rt++)
      af[rt] = *(const bf16x8*)(shA + (rt * 16 + l) * KPAD + s * 32 + q * 8);
#pragma unroll
    for (int ct = 0; ct < 4; ct++)
      bfr[ct] = *(const bf16x8*)(Bp + (s * 4 + q) * 2048 + colbase8 + ct * 128);
#pragma unroll
    for (int rt = 0; rt < 4; rt++)
#pragma unroll
      for (int ct = 0; ct < 4; ct++)
        acc[rt][ct] = __builtin_amdgcn_mfma_f32_16x16x32_bf16(af[rt], bfr[ct], acc[rt][ct], 0, 0, 0);
  }
}

__global__ __launch_bounds__(256, 2)
void gat_poly_kernel(const float* __restrict__ x,
                     const float* __restrict__ as0, const float* __restrict__ at0, const float* __restrict__ b0,
                     const float* __restrict__ as1, const float* __restrict__ at1, const float* __restrict__ b1,
                     const float* __restrict__ as2, const float* __restrict__ at2, const float* __restrict__ b2,
                     const float* __restrict__ as3, const float* __restrict__ at3, const float* __restrict__ b3,
                     const float* __restrict__ h1b, const float* __restrict__ h2b,
                     const __bf16* __restrict__ WP,    // packed weights (d_ws)
                     const float* __restrict__ h2wt,   // 2x256 transposed head
                     const float* __restrict__ d_temb, // 2048x128 precomputed temb
                     float* __restrict__ out)
{
  __shared__ __bf16 sh_hb[VN * KPAD];   // activations bf16 (MFMA A source)
  __shared__ __bf16 sh_pb[VN * PPAD];   // proj spill bf16
  __shared__ float  sh_temb[128];
  __shared__ float  sh_ssp[VN * 4];
  __shared__ float  sh_stp[VN * 4];
  __shared__ float  sh_al[VN][4][3];

  const int b    = blockIdx.x;
  const int tid  = threadIdx.x;
  const int w    = tid >> 6;
  const int lane = tid & 63;
  const int l    = lane & 15;
  const int q    = lane >> 4;
  const int cb   = w * 64;
  const int colbase8 = (cb + l) * 8;

  float h_reg[4][4][4];   // lane's fp32 h[n][f] in C-layout ownership

  if (tid < 128) sh_temb[tid] = d_temb[b * 128 + tid];
  __syncthreads();

  // ------------- h0 = [coords(2), pos(4), temb(128)], zero pad to 160 --------
  for (int idx = tid; idx < VN * 160; idx += 256) {
    int n = idx / 160, k = idx - n * 160;
    float v = 0.0f;
    if (k < 2) {
      v = x[b * 128 + 2 * n + k];
    } else if (k < 6) {
      float ph  = (float)n * 0.09817477042468103f;  // 2*pi/64
      float arg = (k < 4) ? ph : 2.0f * ph;
      v = ((k & 1) == 0) ? sinf(arg) : cosf(arg);
    } else if (k < 134) {
      v = sh_temb[k - 6];
    }
    sh_hb[n * KPAD + k] = (__bf16)v;
  }
  __syncthreads();

  const int WOFFS[3]  = {OFF_W0, OFF_W1, OFF_W2};
  const int SOFFS[3]  = {OFF_SK0, OFF_SK1, OFF_SK2};
  const float* Asr[3] = {as0, as1, as2};
  const float* Atg[3] = {at0, at1, at2};
  const float* Bs[3]  = {b0, b1, b2};

  // ---------------- GAT layers 0..2 (NH=4, FOUT=64, concat + elu) ------------
  for (int li = 0; li < 3; li++) {
    f32x4 acc[4][4];
#pragma unroll
    for (int rt = 0; rt < 4; rt++)
#pragma unroll
      for (int ct = 0; ct < 4; ct++) acc[rt][ct] = (f32x4)0.0f;

    if (li == 0) mfma_mm<5>(WP + WOFFS[0], acc, sh_hb, l, q, colbase8);
    else         mfma_mm<8>(WP + WOFFS[li], acc, sh_hb, l, q, colbase8);

    { // scores from acc registers; wave w == head w
      const float* av = Asr[li];
      const float* tv = Atg[li];
      float a0 = av[cb + l], a1 = av[cb + 16 + l], a2 = av[cb + 32 + l], a3 = av[cb + 48 + l];
      float t0 = tv[cb + l], t1 = tv[cb + 16 + l], t2 = tv[cb + 32 + l], t3 = tv[cb + 48 + l];
#pragma unroll
      for (int rt = 0; rt < 4; rt++)
#pragma unroll
        for (int reg = 0; reg < 4; reg++) {
          float ss = acc[rt][0][reg] * a0 + acc[rt][1][reg] * a1
                   + acc[rt][2][reg] * a2 + acc[rt][3][reg] * a3;
          float st = acc[rt][0][reg] * t0 + acc[rt][1][reg] * t1
                   + acc[rt][2][reg] * t2 + acc[rt][3][reg] * t3;
#pragma unroll
          for (int m = 8; m >= 1; m >>= 1) {
            ss += __shfl_xor(ss, m, 64);
            st += __shfl_xor(st, m, 64);
          }
          if (l == 0) {
            int n = rt * 16 + q * 4 + reg;
            sh_ssp[n * 4 + w] = ss;
            sh_stp[n * 4 + w] = st;
          }
        }
    }
    // spill proj to LDS (bf16)
#pragma unroll
    for (int rt = 0; rt < 4; rt++)
#pragma unroll
      for (int ct = 0; ct < 4; ct++)
#pragma unroll
        for (int reg = 0; reg < 4; reg++)
          sh_pb[(rt * 16 + q * 4 + reg) * PPAD + cb + ct * 16 + l] = (__bf16)acc[rt][ct][reg];
    __syncthreads();

    { // softmax over 3 incoming edges, thread per (node, head)
      int n = tid >> 2, hd = tid & 3;
      int prv = (n + 63) & 63, nxt = (n + 1) & 63;
      float stg = sh_stp[n * 4 + hd];
      float e0 = sh_ssp[prv * 4 + hd] + stg; e0 = (e0 < 0.0f) ? 0.2f * e0 : e0;
      float e1 = sh_ssp[nxt * 4 + hd] + stg; e1 = (e1 < 0.0f) ? 0.2f * e1 : e1;
      float e2 = sh_ssp[n * 4 + hd]   + stg; e2 = (e2 < 0.0f) ? 0.2f * e2 : e2;
      float m  = fmaxf(e0, fmaxf(e1, e2));
      float x0 = expf(e0 - m), x1 = expf(e1 - m), x2 = expf(e2 - m);
      float dn = x0 + x1 + x2 + 1e-16f;
      sh_al[n][hd][0] = x0 / dn;
      sh_al[n][hd][1] = x1 / dn;
      sh_al[n][hd][2] = x2 / dn;
    }

    // skip projection
#pragma unroll
    for (int rt = 0; rt < 4; rt++)
#pragma unroll
      for (int ct = 0; ct < 4; ct++) acc[rt][ct] = (f32x4)0.0f;
    if (li == 0) mfma_mm<5>(WP + SOFFS[0], acc, sh_hb, l, q, colbase8);
    else         mfma_mm<8>(WP + SOFFS[li], acc, sh_hb, l, q, colbase8);
    __syncthreads();   // alphas ready; all waves done with sh_hb

    { // epilogue: out = skip + sum alpha*proj[src] + b; elu
      const float* bb = Bs[li];
      float b4[4];
#pragma unroll
      for (int ct = 0; ct < 4; ct++) b4[ct] = bb[cb + ct * 16 + l];
#pragma unroll
      for (int rt = 0; rt < 4; rt++)
#pragma unroll
        for (int reg = 0; reg < 4; reg++) {
          int n = rt * 16 + q * 4 + reg;
          int prv = (n + 63) & 63, nxt = (n + 1) & 63;
          float a0 = sh_al[n][w][0], a1 = sh_al[n][w][1], a2 = sh_al[n][w][2];
#pragma unroll
          for (int ct = 0; ct < 4; ct++) {
            int f = cb + ct * 16 + l;
            float o = acc[rt][ct][reg]
                    + a0 * (float)sh_pb[prv * PPAD + f]
                    + a1 * (float)sh_pb[nxt * PPAD + f]
                    + a2 * (float)sh_pb[n * PPAD + f] + b4[ct];
            o = (o > 0.0f) ? o : (expf(o) - 1.0f);
            h_reg[rt][ct][reg] = o;
            sh_hb[n * KPAD + f] = (__bf16)o;
          }
        }
    }
    __syncthreads();
  }

  // ---------------- GAT layer 3 (NH=1, FOUT=256, identity skip, no act) ------
  {
    f32x4 acc[4][4];
#pragma unroll
    for (int rt = 0; rt < 4; rt++)
#pragma unroll
      for (int ct = 0; ct < 4; ct++) acc[rt][ct] = (f32x4)0.0f;
    mfma_mm<8>(WP + OFF_W3, acc, sh_hb, l, q, colbase8);

    { // per-wave partial scores over this wave's 64 cols
      float a0 = as3[cb + l], a1 = as3[cb + 16 + l], a2 = as3[cb + 32 + l], a3 = as3[cb + 48 + l];
      float t0 = at3[cb + l], t1 = at3[cb + 16 + l], t2 = at3[cb + 32 + l], t3 = at3[cb + 48 + l];
#pragma unroll
      for (int rt = 0; rt < 4; rt++)
#pragma unroll
        for (int reg = 0; reg < 4; reg++) {
          float ss = acc[rt][0][reg] * a0 + acc[rt][1][reg] * a1
                   + acc[rt][2][reg] * a2 + acc[rt][3][reg] * a3;
          float st = acc[rt][0][reg] * t0 + acc[rt][1][reg] * t1
                   + acc[rt][2][reg] * t2 + acc[rt][3][reg] * t3;
#pragma unroll
          for (int m = 8; m >= 1; m >>= 1) {
            ss += __shfl_xor(ss, m, 64);
            st += __shfl_xor(st, m, 64);
          }
          if (l == 0) {
            int n = rt * 16 + q * 4 + reg;
            sh_ssp[n * 4 + w] = ss;
            sh_stp[n * 4 + w] = st;
          }
        }
    }
#pragma unroll
    for (int rt = 0; rt < 4; rt++)
#pragma unroll
      for (int ct = 0; ct < 4; ct++)
#pragma unroll
        for (int reg = 0; reg < 4; reg++)
          sh_pb[(rt * 16 + q * 4 + reg) * PPAD + cb + ct * 16 + l] = (__bf16)acc[rt][ct][reg];
    __syncthreads();

    if (tid < 64) {  // single head: combine wave partials, then softmax
      int n = tid;
      float ssn = sh_ssp[n * 4] + sh_ssp[n * 4 + 1] + sh_ssp[n * 4 + 2] + sh_ssp[n * 4 + 3];
      float stn = sh_stp[n * 4] + sh_stp[n * 4 + 1] + sh_stp[n * 4 + 2] + sh_stp[n * 4 + 3];
      sh_ssp[n * 4] = ssn;
      sh_stp[n * 4] = stn;
    }
    __syncthreads();
    if (tid < 64) {
      int n = tid;
      int prv = (n + 63) & 63, nxt = (n + 1) & 63;
      float stg = sh_stp[n * 4];
      float e0 = sh_ssp[prv * 4] + stg; e0 = (e0 < 0.0f) ? 0.2f * e0 : e0;
      float e1 = sh_ssp[nxt * 4] + stg; e1 = (e1 < 0.0f) ? 0.2f * e1 : e1;
      float e2 = sh_ssp[n * 4]   + stg; e2 = (e2 < 0.0f) ? 0.2f * e2 : e2;
      float m  = fmaxf(e0, fmaxf(e1, e2));
      float x0 = expf(e0 - m), x1 = expf(e1 - m), x2 = expf(e2 - m);
      float dn = x0 + x1 + x2 + 1e-16f;
      sh_al[n][0][0] = x0 / dn;
      sh_al[n][0][1] = x1 / dn;
      sh_al[n][0][2] = x2 / dn;
    }
    __syncthreads();

    { // epilogue: out = agg + h (identity residual) + b3
      float b4[4];
#pragma unroll
      for (int ct = 0; ct < 4; ct++) b4[ct] = b3[cb + ct * 16 + l];
#pragma unroll
      for (int rt = 0; rt < 4; rt++)
#pragma unroll
        for (int reg = 0; reg < 4; reg++) {
          int n = rt * 16 + q * 4 + reg;
          int prv = (n + 63) & 63, nxt = (n + 1) & 63;
          float a0 = sh_al[n][0][0], a1 = sh_al[n][0][1], a2 = sh_al[n][0][2];
#pragma unroll
          for (int ct = 0; ct < 4; ct++) {
            int f = cb + ct * 16 + l;
            float o = a0 * (float)sh_pb[prv * PPAD + f]
                    + a1 * (float)sh_pb[nxt * PPAD + f]
                    + a2 * (float)sh_pb[n * PPAD + f]
                    + h_reg[rt][ct][reg] + b4[ct];
            h_reg[rt][ct][reg] = o;
            sh_hb[n * KPAD + f] = (__bf16)o;
          }
        }
    }
    __syncthreads();
  }

  // ---------------- head MLP: silu(h@h1W+h1b), then h@h2W+h2b ----------------
  {
    f32x4 acc[4][4];
#pragma unroll
    for (int rt = 0; rt < 4; rt++)
#pragma unroll
      for (int ct = 0; ct < 4; ct++) acc[rt][ct] = (f32x4)0.0f;
    mfma_mm<8>(WP + OFF_H1W, acc, sh_hb, l, q, colbase8);
    __syncthreads();

    float b4[4];
#pragma unroll
    for (int ct = 0; ct < 4; ct++) b4[ct] = h1b[cb + ct * 16 + l];
#pragma unroll
    for (int rt = 0; rt < 4; rt++)
#pragma unroll
      for (int reg = 0; reg < 4; reg++) {
        int n = rt * 16 + q * 4 + reg;
#pragma unroll
        for (int ct = 0; ct < 4; ct++) {
          int f = cb + ct * 16 + l;
          float o = acc[rt][ct][reg] + b4[ct];
          o = o / (1.0f + expf(-o));
          sh_hb[n * KPAD + f] = (__bf16)o;
        }
      }
    __syncthreads();

    if (tid < 128) {  // final 256 -> 2, vectorized
      int n = tid >> 1, c = tid & 1;
      const float* wrow = h2wt + c * 256;
      float o = h2b[c];
#pragma unroll 4
      for (int k8 = 0; k8 < 32; k8++) {
        bf16x8 hv = *(const bf16x8*)(sh_hb + n * KPAD + k8 * 8);
        f32x4 w0 = *(const f32x4*)(wrow + k8 * 8);
        f32x4 w1 = *(const f32x4*)(wrow + k8 * 8 + 4);
#pragma unroll
        for (int j = 0; j < 4; j++) o = fmaf((float)hv[j], w0[j], o);
#pragma unroll
        for (int j = 0; j < 4; j++) o = fmaf((float)hv[4 + j], w1[j], o);
      }
      out[b * 128 + 2 * n + c] = o;
    }
  }
}

extern "C" void kernel_launch(void* const* d_in, const int* in_sizes, int n_in,
                              void* d_out, int out_size, void* d_ws, size_t ws_size,
                              hipStream_t stream)
{
  auto fp = [&](int i) { return (const float*)d_in[i]; };
  __bf16* wp   = (__bf16*)d_ws;
  float* h2wt  = (float*)(wp + OFF_END);        // 512 fp32
  float* dtemb = h2wt + 512;                    // 2048*128 fp32

  conv_pack<<<160, 256, 0, stream>>>(fp(4),  wp + OFF_W0,  134, 160);
  conv_pack<<<160, 256, 0, stream>>>(fp(20), wp + OFF_SK0, 134, 160);
  conv_pack<<<256, 256, 0, stream>>>(fp(8),  wp + OFF_W1,  256, 256);
  conv_pack<<<256, 256, 0, stream>>>(fp(21), wp + OFF_SK1, 256, 256);
  conv_pack<<<256, 256, 0, stream>>>(fp(12), wp + OFF_W2,  256, 256);
  conv_pack<<<256, 256, 0, stream>>>(fp(22), wp + OFF_SK2, 256, 256);
  conv_pack<<<256, 256, 0, stream>>>(fp(16), wp + OFF_W3,  256, 256);
  conv_pack<<<256, 256, 0, stream>>>(fp(23), wp + OFF_H1W, 256, 256);
  transpose_h2w<<<1, 512, 0, stream>>>(fp(25), h2wt);
  temb_kernel<<<2048, 128, 0, stream>>>((const int*)d_in[1], fp(2), fp(3), dtemb);

  gat_poly_kernel<<<2048, 256, 0, stream>>>(
      fp(0),
      fp(5),  fp(6),  fp(7),
      fp(9),  fp(10), fp(11),
      fp(13), fp(14), fp(15),
      fp(17), fp(18), fp(19),
      fp(24), fp(26),
      wp, h2wt, dtemb,
      (float*)d_out);
}